// Round 8
// baseline (262.222 us; speedup 1.0000x reference)
//
#include <hip/hip_runtime.h>
#include <stdint.h>

typedef unsigned short u16;
typedef __bf16 bf16x8 __attribute__((ext_vector_type(8)));
typedef u16 u16x8 __attribute__((ext_vector_type(8)));
typedef u16 u16x4 __attribute__((ext_vector_type(4)));
typedef float f32x4 __attribute__((ext_vector_type(4)));
typedef float f32x16 __attribute__((ext_vector_type(16)));

#define SEQ 4096
#define CD 1024
#define NH 16
#define DHD 64

__device__ __forceinline__ u16 f2bf(float f) {
  union { float f; unsigned u; } v; v.f = f;
  unsigned r = v.u + 0x7fffu + ((v.u >> 16) & 1u);
  return (u16)(r >> 16);
}
__device__ __forceinline__ unsigned fbits(float f) {
  union { float f; unsigned u; } v; v.f = f; return v.u;
}

// ---------------- convert fp32 -> bf16 ----------------
__global__ __launch_bounds__(256) void cvt_bf16(const float* __restrict__ in, u16* __restrict__ out, int n) {
  int i = (blockIdx.x * 256 + threadIdx.x) * 8;
  if (i >= n) return;
  float4 a = *(const float4*)(in + i);
  float4 b = *(const float4*)(in + i + 4);
  u16x8 o;
  o[0] = f2bf(a.x); o[1] = f2bf(a.y); o[2] = f2bf(a.z); o[3] = f2bf(a.w);
  o[4] = f2bf(b.x); o[5] = f2bf(b.y); o[6] = f2bf(b.z); o[7] = f2bf(b.w);
  *(u16x8*)(out + i) = o;
}

// ---------------- GEMM core: out = (A * Bw^T + bias) * oscale ----------------
// MODE 0: bf16 out[row*CD+col]; MODE 1: bf16 TRANSPOSED out[col*SEQ+row]; MODE 2: f32 out[row*CD+col].
// Staging: reg-roundtrip double-buffer (attn-kernel pattern) — ONE barrier per k-iter,
// prefetch loads live in registers across the barrier (no vmcnt(0)-before-barrier drain).
template<int MODE>
__device__ __forceinline__ void gemm_core(const u16* __restrict__ A, const u16* __restrict__ Bw,
                                          const float* __restrict__ bias, void* __restrict__ outp,
                                          float oscale) {
  constexpr int K = CD, N = CD;
  __shared__ u16 As[2][128 * 32];
  __shared__ u16 Bs[2][128 * 32];
  const int tid = threadIdx.x;
  const int w = tid >> 6, L = tid & 63, q = L >> 4, ln = L & 15;
  const int rowA0 = blockIdx.y * 128, rowB0 = blockIdx.x * 128;
  const int wr = (w >> 1) * 64, wc = (w & 1) * 64;
  // staging map: 2 chunks x 16B per thread per matrix; byte off c*4096 + tid*16
  const int c0 = tid * 16, c1 = 4096 + tid * 16;
  const int r0 = c0 >> 6, e0 = (c0 & 63) >> 1;   // 64B per row (32 bf16)
  const int r1 = c1 >> 6, e1 = (c1 & 63) >> 1;
  f32x4 acc[4][4] = {};
  u16x8 a0, a1, b0, b1;
  a0 = *(const u16x8*)(A  + (size_t)(rowA0 + r0) * K + e0);
  a1 = *(const u16x8*)(A  + (size_t)(rowA0 + r1) * K + e1);
  b0 = *(const u16x8*)(Bw + (size_t)(rowB0 + r0) * K + e0);
  b1 = *(const u16x8*)(Bw + (size_t)(rowB0 + r1) * K + e1);
  for (int k0 = 0; k0 < K; k0 += 32) {
    const int buf = (k0 >> 5) & 1;
    *(u16x8*)(&As[buf][c0 >> 1]) = a0;
    *(u16x8*)(&As[buf][c1 >> 1]) = a1;
    *(u16x8*)(&Bs[buf][c0 >> 1]) = b0;
    *(u16x8*)(&Bs[buf][c1 >> 1]) = b1;
    __syncthreads();  // single barrier per iter; WAR vs iter-2 reads guarded by iter-1 sync
    if (k0 + 32 < K) {  // prefetch next k-slice; stays in flight through the MFMAs below
      a0 = *(const u16x8*)(A  + (size_t)(rowA0 + r0) * K + k0 + 32 + e0);
      a1 = *(const u16x8*)(A  + (size_t)(rowA0 + r1) * K + k0 + 32 + e1);
      b0 = *(const u16x8*)(Bw + (size_t)(rowB0 + r0) * K + k0 + 32 + e0);
      b1 = *(const u16x8*)(Bw + (size_t)(rowB0 + r1) * K + k0 + 32 + e1);
    }
    bf16x8 af[4], bg[4];
#pragma unroll
    for (int i = 0; i < 4; ++i) af[i] = *(const bf16x8*)(&As[buf][(wr + i * 16 + ln) * 32 + q * 8]);
#pragma unroll
    for (int i = 0; i < 4; ++i) bg[i] = *(const bf16x8*)(&Bs[buf][(wc + i * 16 + ln) * 32 + q * 8]);
#pragma unroll
    for (int i = 0; i < 4; ++i)
#pragma unroll
      for (int j = 0; j < 4; ++j)
        acc[i][j] = __builtin_amdgcn_mfma_f32_16x16x32_bf16(af[i], bg[j], acc[i][j], 0, 0, 0);
  }
#pragma unroll
  for (int i = 0; i < 4; ++i) {
#pragma unroll
    for (int j = 0; j < 4; ++j) {
      int col = rowB0 + wc + j * 16 + ln;
      float bb = bias[col];
#pragma unroll
      for (int r = 0; r < 4; ++r) {
        int row = rowA0 + wr + i * 16 + q * 4 + r;
        float v = (acc[i][j][r] + bb) * oscale;
        if (MODE == 0)      ((u16*)outp)[(size_t)row * N + col] = f2bf(v);
        else if (MODE == 1) ((u16*)outp)[(size_t)col * SEQ + row] = f2bf(v);
        else                ((float*)outp)[(size_t)row * N + col] = v;
      }
    }
  }
}

__global__ __launch_bounds__(256) void gemm_qkv(const u16* __restrict__ A, const u16* __restrict__ W3,
                                                const float* __restrict__ bq, const float* __restrict__ bk,
                                                const float* __restrict__ bv, u16* __restrict__ Qb,
                                                u16* __restrict__ Kb, u16* __restrict__ VTb) {
  int z = blockIdx.z;
  if (z == 0)      gemm_core<0>(A, W3,               bq, Qb,  0.03125f);  // softmax scale folded
  else if (z == 1) gemm_core<0>(A, W3 + CD * CD,     bk, Kb,  1.0f);
  else             gemm_core<1>(A, W3 + 2 * CD * CD, bv, VTb, 1.0f);      // V stored transposed
}

__global__ __launch_bounds__(256) void gemm_proj(const u16* __restrict__ A, const u16* __restrict__ Bw,
                                                 const float* __restrict__ bias, float* __restrict__ out) {
  gemm_core<2>(A, Bw, bias, out, 1.0f);
}

// ---------------- flash attention (causal), 64 q-rows/block, 2 waves, S^T form ----------------
// VERBATIM round-4 kernel (verified, ~90 µs). Q pre-scaled by C^-0.5. No running max.
__global__ __launch_bounds__(128) void attn_kernel(const u16* __restrict__ Q, const u16* __restrict__ Kg,
                                                   const u16* __restrict__ VTg, u16* __restrict__ O) {
  __shared__ u16 Ks[2][64 * 72];
  __shared__ u16 Vt[2][64 * 72];
  const int tid = threadIdx.x, w = tid >> 6, L = tid & 63;
  const int ln = L & 31, hh = L >> 5;
  const int b = blockIdx.x;
  const int qt = (SEQ / 64 - 1) - (b >> 4);  // descending length (LPT)
  const int h = b & 15;
  const int colH = h * DHD;
  const int qrow0 = qt * 64 + w * 32;
  bf16x8 qf[4];
#pragma unroll
  for (int kk = 0; kk < 4; ++kk)
    qf[kk] = *(const bf16x8*)(Q + (size_t)(qrow0 + ln) * CD + colH + kk * 16 + hh * 8);
  f32x16 oa[2] = {};
  float lsum = 0.f;
  const int srow = tid >> 3, sx = tid & 7;
  u16x8 kr[4], vr[4];
#pragma unroll
  for (int p = 0; p < 4; ++p) {
    kr[p] = *(const u16x8*)(Kg + (size_t)(p * 16 + srow) * CD + colH + sx * 8);
    vr[p] = *(const u16x8*)(VTg + (size_t)(colH + p * 16 + srow) * SEQ + sx * 8);
  }
  for (int jt = 0; jt <= qt; ++jt) {
    const int buf = jt & 1;
    u16* KsB = Ks[buf];
    u16* VtB = Vt[buf];
#pragma unroll
    for (int p = 0; p < 4; ++p) {
      *(u16x8*)(KsB + (p * 16 + srow) * 72 + sx * 8) = kr[p];
      *(u16x8*)(VtB + (p * 16 + srow) * 72 + sx * 8) = vr[p];
    }
    __syncthreads();
    if (jt < qt) {
      const size_t kb2 = (size_t)(jt + 1) * 64;
#pragma unroll
      for (int p = 0; p < 4; ++p) {
        kr[p] = *(const u16x8*)(Kg + (kb2 + p * 16 + srow) * CD + colH + sx * 8);
        vr[p] = *(const u16x8*)(VTg + (size_t)(colH + p * 16 + srow) * SEQ + kb2 + sx * 8);
      }
    }
    const bool diag = (jt == qt);
    unsigned pk[16];
#pragma unroll
    for (int nt = 0; nt < 2; ++nt) {
      f32x16 a = {};
#pragma unroll
      for (int kk = 0; kk < 4; ++kk) {
        bf16x8 kf = *(const bf16x8*)(KsB + (nt * 32 + ln) * 72 + kk * 16 + hh * 8);
        a = __builtin_amdgcn_mfma_f32_32x32x16_bf16(kf, qf[kk], a, 0, 0, 0);
      }
#pragma unroll
      for (int r = 0; r < 16; ++r) {
        float sv = a[r];
        if (diag) {
          const int key_l = nt * 32 + (r & 3) + 8 * (r >> 2) + 4 * hh;
          if (key_l > w * 32 + ln) sv = -1e30f;
        }
        float p = __expf(sv);
        lsum += p;
        a[r] = p;
      }
#pragma unroll
      for (int i = 0; i < 8; ++i)
        pk[nt * 8 + i] = __builtin_amdgcn_perm(fbits(a[2 * i + 1]), fbits(a[2 * i]), 0x07060302);
    }
#pragma unroll
    for (int b0 = 0; b0 < 16; b0 += 4) {
      asm("v_permlane32_swap_b32 %0, %1" : "+v"(pk[b0 + 0]), "+v"(pk[b0 + 2]));
      asm("v_permlane32_swap_b32 %0, %1" : "+v"(pk[b0 + 1]), "+v"(pk[b0 + 3]));
    }
#pragma unroll
    for (int g = 0; g < 2; ++g)
#pragma unroll
      for (int s = 0; s < 4; ++s) {
        bf16x8 vf = *(const bf16x8*)(VtB + (g * 32 + ln) * 72 + s * 16 + hh * 8);
        union { unsigned u[4]; bf16x8 v; } pf;
        pf.u[0] = pk[s * 4 + 0]; pf.u[1] = pk[s * 4 + 1];
        pf.u[2] = pk[s * 4 + 2]; pf.u[3] = pk[s * 4 + 3];
        oa[g] = __builtin_amdgcn_mfma_f32_32x32x16_bf16(vf, pf.v, oa[g], 0, 0, 0);
      }
  }
  lsum += __shfl_xor(lsum, 32, 64);
  const float inv = 1.0f / lsum;
#pragma unroll
  for (int g = 0; g < 2; ++g)
#pragma unroll
    for (int rg = 0; rg < 4; ++rg) {
      u16x4 ov;
#pragma unroll
      for (int i = 0; i < 4; ++i) ov[i] = f2bf(oa[g][rg * 4 + i] * inv);
      *(u16x4*)(O + (size_t)(qrow0 + ln) * CD + colH + g * 32 + 8 * rg + 4 * hh) = ov;
    }
}

extern "C" void kernel_launch(void* const* d_in, const int* in_sizes, int n_in,
                              void* d_out, int out_size, void* d_ws, size_t ws_size,
                              hipStream_t stream) {
  const float* x  = (const float*)d_in[0];
  const float* Wq = (const float*)d_in[1];
  const float* bq = (const float*)d_in[2];
  const float* Wk = (const float*)d_in[3];
  const float* bk = (const float*)d_in[4];
  const float* Wv = (const float*)d_in[5];
  const float* bv = (const float*)d_in[6];
  const float* Wp = (const float*)d_in[7];
  const float* bp = (const float*)d_in[8];

  char* ws = (char*)d_ws;
  u16* xb  = (u16*)(ws);                        // 8 MiB : x bf16
  u16* Wb  = (u16*)(ws + (8u << 20));           // 6 MiB : Wq,Wk,Wv bf16
  u16* Wpb = (u16*)(ws + (14u << 20));          // 2 MiB : Wp bf16
  u16* Qb  = (u16*)(ws + (16u << 20));          // 8 MiB : Q (pre-scaled by 1/32)
  u16* Kb  = (u16*)(ws + (24u << 20));          // 8 MiB
  u16* VTb = (u16*)(ws + (32u << 20));          // 8 MiB : V transposed [1024][4096]
  u16* Ab  = (u16*)(ws + (40u << 20));          // 8 MiB : attention output bf16

  cvt_bf16<<<2048, 256, 0, stream>>>(x,  xb, SEQ * CD);
  cvt_bf16<<<512, 256, 0, stream>>>(Wq, Wb,               CD * CD);
  cvt_bf16<<<512, 256, 0, stream>>>(Wk, Wb + CD * CD,     CD * CD);
  cvt_bf16<<<512, 256, 0, stream>>>(Wv, Wb + 2 * CD * CD, CD * CD);
  cvt_bf16<<<512, 256, 0, stream>>>(Wp, Wpb,              CD * CD);

  gemm_qkv<<<dim3(CD / 128, SEQ / 128, 3), 256, 0, stream>>>(xb, Wb, bq, bk, bv, Qb, Kb, VTb);
  attn_kernel<<<(SEQ / 64) * NH, 128, 0, stream>>>(Qb, Kb, VTb, Ab);
  gemm_proj<<<dim3(CD / 128, SEQ / 128), 256, 0, stream>>>(Ab, Wpb, bp, (float*)d_out);
}

// Round 9
// 241.320 us; speedup vs baseline: 1.0866x; 1.0866x over previous
//
#include <hip/hip_runtime.h>
#include <stdint.h>

typedef unsigned short u16;
typedef __bf16 bf16x8 __attribute__((ext_vector_type(8)));
typedef u16 u16x8 __attribute__((ext_vector_type(8)));
typedef u16 u16x4 __attribute__((ext_vector_type(4)));
typedef float f32x4 __attribute__((ext_vector_type(4)));
typedef float f32x16 __attribute__((ext_vector_type(16)));

#define SEQ 4096
#define CD 1024
#define NH 16
#define DHD 64

__device__ __forceinline__ u16 f2bf(float f) {
  union { float f; unsigned u; } v; v.f = f;
  unsigned r = v.u + 0x7fffu + ((v.u >> 16) & 1u);
  return (u16)(r >> 16);
}
__device__ __forceinline__ unsigned fbits(float f) {
  union { float f; unsigned u; } v; v.f = f; return v.u;
}

__device__ __forceinline__ void load_lds16(const u16* g, u16* l) {
  __builtin_amdgcn_global_load_lds((const __attribute__((address_space(1))) void*)g,
                                   (__attribute__((address_space(3))) void*)l, 16, 0, 0);
}

// ---------------- convert fp32 -> bf16 ----------------
__global__ __launch_bounds__(256) void cvt_bf16(const float* __restrict__ in, u16* __restrict__ out, int n) {
  int i = (blockIdx.x * 256 + threadIdx.x) * 8;
  if (i >= n) return;
  float4 a = *(const float4*)(in + i);
  float4 b = *(const float4*)(in + i + 4);
  u16x8 o;
  o[0] = f2bf(a.x); o[1] = f2bf(a.y); o[2] = f2bf(a.z); o[3] = f2bf(a.w);
  o[4] = f2bf(b.x); o[5] = f2bf(b.y); o[6] = f2bf(b.z); o[7] = f2bf(b.w);
  *(u16x8*)(out + i) = o;
}

// ---------------- GEMM core (r4-verified, global_load_lds staging): out = (A*Bw^T + bias)*oscale --
// MODE 0: bf16 out[row*CD+col]; MODE 1: bf16 TRANSPOSED out[col*SEQ+row]; MODE 2: f32 out[row*CD+col]
template<int MODE>
__device__ __forceinline__ void gemm_core(const u16* __restrict__ A, const u16* __restrict__ Bw,
                                          const float* __restrict__ bias, void* __restrict__ outp,
                                          float oscale) {
  constexpr int K = CD, N = CD;
  __shared__ u16 As[128 * 32];
  __shared__ u16 Bs[128 * 32];
  const int tid = threadIdx.x;
  const int w = tid >> 6, L = tid & 63, q = L >> 4, ln = L & 15;
  const int rowA0 = blockIdx.y * 128, rowB0 = blockIdx.x * 128;
  const int wr = (w >> 1) * 64, wc = (w & 1) * 64;
  f32x4 acc[4][4] = {};
  for (int k0 = 0; k0 < K; k0 += 32) {
#pragma unroll
    for (int pass = 0; pass < 2; ++pass) {
      int off = pass * 4096 + tid * 16;
      int row = off >> 6;
      int cole = (off & 63) >> 1;
      load_lds16(A + (size_t)(rowA0 + row) * K + k0 + cole, As + pass * 2048 + w * 512);
      load_lds16(Bw + (size_t)(rowB0 + row) * K + k0 + cole, Bs + pass * 2048 + w * 512);
    }
    __syncthreads();
    bf16x8 af[4], bg[4];
#pragma unroll
    for (int i = 0; i < 4; ++i) af[i] = *(const bf16x8*)(As + (wr + i * 16 + ln) * 32 + q * 8);
#pragma unroll
    for (int i = 0; i < 4; ++i) bg[i] = *(const bf16x8*)(Bs + (wc + i * 16 + ln) * 32 + q * 8);
#pragma unroll
    for (int i = 0; i < 4; ++i)
#pragma unroll
      for (int j = 0; j < 4; ++j)
        acc[i][j] = __builtin_amdgcn_mfma_f32_16x16x32_bf16(af[i], bg[j], acc[i][j], 0, 0, 0);
    __syncthreads();
  }
#pragma unroll
  for (int i = 0; i < 4; ++i) {
#pragma unroll
    for (int j = 0; j < 4; ++j) {
      int col = rowB0 + wc + j * 16 + ln;
      float bb = bias[col];
#pragma unroll
      for (int r = 0; r < 4; ++r) {
        int row = rowA0 + wr + i * 16 + q * 4 + r;
        float v = (acc[i][j][r] + bb) * oscale;
        if (MODE == 0)      ((u16*)outp)[(size_t)row * N + col] = f2bf(v);
        else if (MODE == 1) ((u16*)outp)[(size_t)col * SEQ + row] = f2bf(v);
        else                ((float*)outp)[(size_t)row * N + col] = v;
      }
    }
  }
}

__global__ __launch_bounds__(256) void gemm_qkv(const u16* __restrict__ A, const u16* __restrict__ W3,
                                                const float* __restrict__ bq, const float* __restrict__ bk,
                                                const float* __restrict__ bv, u16* __restrict__ Qb,
                                                u16* __restrict__ Kb, u16* __restrict__ VTb) {
  int z = blockIdx.z;
  // Q scale = C^-0.5 * log2(e), so attention can use exp2 directly (saves a v_mul per S element)
  if (z == 0)      gemm_core<0>(A, W3,               bq, Qb,  0.0450842225f);
  else if (z == 1) gemm_core<0>(A, W3 + CD * CD,     bk, Kb,  1.0f);
  else             gemm_core<1>(A, W3 + 2 * CD * CD, bv, VTb, 1.0f);      // V stored transposed
}

__global__ __launch_bounds__(256) void gemm_proj(const u16* __restrict__ A, const u16* __restrict__ Bw,
                                                 const float* __restrict__ bias, float* __restrict__ out) {
  gemm_core<2>(A, Bw, bias, out, 1.0f);
}

// ---------------- flash attention (causal), 64 q-rows/block, 2 waves, S^T form ----------------
// r4-verified body. Q pre-scaled by C^-0.5*log2e -> P = exp2(S'). No running max.
// Launched with 18 KB UNUSED dynamic LDS: 36.9+18 = 55.3 KB/block -> 2 blocks/CU ->
// 4 waves on 4 SIMDs = 1 wave/SIMD, eliminating VALU contention on the exp-heavy
// critical chain (qt=63 block: 64 serial tiles sets the kernel duration).
__global__ __launch_bounds__(128) void attn_kernel(const u16* __restrict__ Q, const u16* __restrict__ Kg,
                                                   const u16* __restrict__ VTg, u16* __restrict__ O) {
  __shared__ u16 Ks[2][64 * 72];
  __shared__ u16 Vt[2][64 * 72];
  const int tid = threadIdx.x, w = tid >> 6, L = tid & 63;
  const int ln = L & 31, hh = L >> 5;
  const int b = blockIdx.x;
  const int qt = (SEQ / 64 - 1) - (b >> 4);  // descending length (LPT)
  const int h = b & 15;
  const int colH = h * DHD;
  const int qrow0 = qt * 64 + w * 32;
  bf16x8 qf[4];
#pragma unroll
  for (int kk = 0; kk < 4; ++kk)
    qf[kk] = *(const bf16x8*)(Q + (size_t)(qrow0 + ln) * CD + colH + kk * 16 + hh * 8);
  f32x16 oa[2] = {};
  float lsum = 0.f;
  const int srow = tid >> 3, sx = tid & 7;
  u16x8 kr[4], vr[4];
#pragma unroll
  for (int p = 0; p < 4; ++p) {
    kr[p] = *(const u16x8*)(Kg + (size_t)(p * 16 + srow) * CD + colH + sx * 8);
    vr[p] = *(const u16x8*)(VTg + (size_t)(colH + p * 16 + srow) * SEQ + sx * 8);
  }
  for (int jt = 0; jt <= qt; ++jt) {
    const int buf = jt & 1;
    u16* KsB = Ks[buf];
    u16* VtB = Vt[buf];
#pragma unroll
    for (int p = 0; p < 4; ++p) {
      *(u16x8*)(KsB + (p * 16 + srow) * 72 + sx * 8) = kr[p];
      *(u16x8*)(VtB + (p * 16 + srow) * 72 + sx * 8) = vr[p];
    }
    __syncthreads();
    if (jt < qt) {
      const size_t kb2 = (size_t)(jt + 1) * 64;
#pragma unroll
      for (int p = 0; p < 4; ++p) {
        kr[p] = *(const u16x8*)(Kg + (kb2 + p * 16 + srow) * CD + colH + sx * 8);
        vr[p] = *(const u16x8*)(VTg + (size_t)(colH + p * 16 + srow) * SEQ + kb2 + sx * 8);
      }
    }
    const bool diag = (jt == qt);
    unsigned pk[16];
#pragma unroll
    for (int nt = 0; nt < 2; ++nt) {
      f32x16 a = {};
#pragma unroll
      for (int kk = 0; kk < 4; ++kk) {
        bf16x8 kf = *(const bf16x8*)(KsB + (nt * 32 + ln) * 72 + kk * 16 + hh * 8);
        a = __builtin_amdgcn_mfma_f32_32x32x16_bf16(kf, qf[kk], a, 0, 0, 0);
      }
#pragma unroll
      for (int r = 0; r < 16; ++r) {
        float sv = a[r];
        if (diag) {
          const int key_l = nt * 32 + (r & 3) + 8 * (r >> 2) + 4 * hh;
          if (key_l > w * 32 + ln) sv = -1e30f;
        }
        float p = __builtin_amdgcn_exp2f(sv);  // Q pre-scaled by log2e: exp2(S') == exp(S)
        lsum += p;
        a[r] = p;
      }
#pragma unroll
      for (int i = 0; i < 8; ++i)
        pk[nt * 8 + i] = __builtin_amdgcn_perm(fbits(a[2 * i + 1]), fbits(a[2 * i]), 0x07060302);
    }
#pragma unroll
    for (int b0 = 0; b0 < 16; b0 += 4) {
      asm("v_permlane32_swap_b32 %0, %1" : "+v"(pk[b0 + 0]), "+v"(pk[b0 + 2]));
      asm("v_permlane32_swap_b32 %0, %1" : "+v"(pk[b0 + 1]), "+v"(pk[b0 + 3]));
    }
#pragma unroll
    for (int g = 0; g < 2; ++g)
#pragma unroll
      for (int s = 0; s < 4; ++s) {
        bf16x8 vf = *(const bf16x8*)(VtB + (g * 32 + ln) * 72 + s * 16 + hh * 8);
        union { unsigned u[4]; bf16x8 v; } pf;
        pf.u[0] = pk[s * 4 + 0]; pf.u[1] = pk[s * 4 + 1];
        pf.u[2] = pk[s * 4 + 2]; pf.u[3] = pk[s * 4 + 3];
        oa[g] = __builtin_amdgcn_mfma_f32_32x32x16_bf16(vf, pf.v, oa[g], 0, 0, 0);
      }
  }
  lsum += __shfl_xor(lsum, 32, 64);
  const float inv = 1.0f / lsum;
#pragma unroll
  for (int g = 0; g < 2; ++g)
#pragma unroll
    for (int rg = 0; rg < 4; ++rg) {
      u16x4 ov;
#pragma unroll
      for (int i = 0; i < 4; ++i) ov[i] = f2bf(oa[g][rg * 4 + i] * inv);
      *(u16x4*)(O + (size_t)(qrow0 + ln) * CD + colH + g * 32 + 8 * rg + 4 * hh) = ov;
    }
}

extern "C" void kernel_launch(void* const* d_in, const int* in_sizes, int n_in,
                              void* d_out, int out_size, void* d_ws, size_t ws_size,
                              hipStream_t stream) {
  const float* x  = (const float*)d_in[0];
  const float* Wq = (const float*)d_in[1];
  const float* bq = (const float*)d_in[2];
  const float* Wk = (const float*)d_in[3];
  const float* bk = (const float*)d_in[4];
  const float* Wv = (const float*)d_in[5];
  const float* bv = (const float*)d_in[6];
  const float* Wp = (const float*)d_in[7];
  const float* bp = (const float*)d_in[8];

  char* ws = (char*)d_ws;
  u16* xb  = (u16*)(ws);                        // 8 MiB : x bf16
  u16* Wb  = (u16*)(ws + (8u << 20));           // 6 MiB : Wq,Wk,Wv bf16
  u16* Wpb = (u16*)(ws + (14u << 20));          // 2 MiB : Wp bf16
  u16* Qb  = (u16*)(ws + (16u << 20));          // 8 MiB : Q (pre-scaled by log2e/32)
  u16* Kb  = (u16*)(ws + (24u << 20));          // 8 MiB
  u16* VTb = (u16*)(ws + (32u << 20));          // 8 MiB : V transposed [1024][4096]
  u16* Ab  = (u16*)(ws + (40u << 20));          // 8 MiB : attention output bf16

  cvt_bf16<<<2048, 256, 0, stream>>>(x,  xb, SEQ * CD);
  cvt_bf16<<<512, 256, 0, stream>>>(Wq, Wb,               CD * CD);
  cvt_bf16<<<512, 256, 0, stream>>>(Wk, Wb + CD * CD,     CD * CD);
  cvt_bf16<<<512, 256, 0, stream>>>(Wv, Wb + 2 * CD * CD, CD * CD);
  cvt_bf16<<<512, 256, 0, stream>>>(Wp, Wpb,              CD * CD);

  gemm_qkv<<<dim3(CD / 128, SEQ / 128, 3), 256, 0, stream>>>(xb, Wb, bq, bk, bv, Qb, Kb, VTb);
  // 18432 B unused dynamic LDS: occupancy shaping to 2 blocks/CU (1 wave/SIMD)
  attn_kernel<<<(SEQ / 64) * NH, 128, 18432, stream>>>(Qb, Kb, VTb, Ab);
  gemm_proj<<<dim3(CD / 128, SEQ / 128), 256, 0, stream>>>(Ab, Wpb, bp, (float*)d_out);
}